// Round 4
// baseline (123.698 us; speedup 1.0000x reference)
//
#include <hip/hip_runtime.h>

namespace {
constexpr int kB = 1024;
constexpr int kN = 40;
constexpr int kE = 64;
constexpr int kP = kN * (kN - 1) / 2;  // 780

using bf16x8 = __attribute__((ext_vector_type(8))) short;
using f32x4  = __attribute__((ext_vector_type(4))) float;

__device__ inline unsigned short f2bf(float x) {  // RNE fp32->bf16
  union { float f; unsigned u; } v; v.f = x;
  return (unsigned short)((v.u + 0x7FFFu + ((v.u >> 16) & 1u)) >> 16);
}
__device__ inline float bf2f(unsigned short u) {
  union { unsigned u; float f; } v; v.u = (unsigned)u << 16;
  return v.f;
}

// ---- inputs (B,N,E) fp32 -> xT (N,B,E) bf16; coalesced on both sides ----
__global__ __launch_bounds__(256) void cvt_neb(const float* __restrict__ in,
                                               unsigned short* __restrict__ xT) {
  const int flat = blockIdx.x * 256 + threadIdx.x;  // one bf16x8 chunk per thread
  const int n    = flat >> 13;                      // 8192 chunks per node
  const int rem  = flat & 8191;
  const int b    = rem >> 3;
  const int ch   = (rem & 7) * 8;
  const float* src = in + ((size_t)b * kN + n) * kE + ch;
  const float4 v0 = ((const float4*)src)[0];
  const float4 v1 = ((const float4*)src)[1];
  bf16x8 o;
  o[0] = (short)f2bf(v0.x); o[1] = (short)f2bf(v0.y);
  o[2] = (short)f2bf(v0.z); o[3] = (short)f2bf(v0.w);
  o[4] = (short)f2bf(v1.x); o[5] = (short)f2bf(v1.y);
  o[6] = (short)f2bf(v1.z); o[7] = (short)f2bf(v1.w);
  *(bf16x8*)(xT + ((size_t)n * kB + b) * kE + ch) = o;
}

// ---- main: block = 2r x 4c node tile (8 pairs) x 256 batches; 8 waves,
// wave = one pair x 256 batches. A-frags in regs (once), p/q lines shared via L1.
// Dots -> LDS -> direct masked store to out (B,P): no transpose kernel.
__global__ __launch_bounds__(512, 4)
void opn_tile(const unsigned short* __restrict__ xT,  // (N,B,E) bf16
              const float* __restrict__ param,         // (E,P,E) fp32
              float* __restrict__ out) {               // (B,1,P) fp32
  __shared__ float dots[2 * 256 * 4];  // [rr][b_local][cc], 8 KB

  const int t    = threadIdx.x;
  const int w    = t >> 6;
  const int L    = t & 63;
  const int col  = L & 15;
  const int quad = L >> 4;

  // decode tile id -> (a, cb): r-group a (rows 2a,2a+1), c-group cb (cols 4cb..+3)
  int a = 0, tx = blockIdx.x;
  for (;;) { const int nb = 10 - ((2 * a + 1) >> 2); if (tx < nb) break; tx -= nb; ++a; }
  const int cb  = ((2 * a + 1) >> 2) + tx;
  const int r0  = 2 * a, c0 = 4 * cb;
  const int gb0 = blockIdx.y * 256;

  // wave -> pair
  const int rr = w >> 2, cc = w & 3;
  const int r = r0 + rr, c = c0 + cc;
  const bool valid = (c > r);

  if (valid) {
    const int i = r * (79 - r) / 2 + c - r - 1;  // reference pair index

    // A-frags: M_i[f,e], A[m=f=16mt+col][k=quad*8+j+32ks] (layout HW-verified R2)
    bf16x8 A[4][2];
#pragma unroll
    for (int mt = 0; mt < 4; ++mt) {
      const float* Mrow = param + ((size_t)(16 * mt + col) * kP + i) * kE + quad * 8;
#pragma unroll
      for (int ks = 0; ks < 2; ++ks) {
        const float4 s0 = *(const float4*)(Mrow + 32 * ks);
        const float4 s1 = *(const float4*)(Mrow + 32 * ks + 4);
        bf16x8 fr;
        fr[0] = (short)f2bf(s0.x); fr[1] = (short)f2bf(s0.y);
        fr[2] = (short)f2bf(s0.z); fr[3] = (short)f2bf(s0.w);
        fr[4] = (short)f2bf(s1.x); fr[5] = (short)f2bf(s1.y);
        fr[6] = (short)f2bf(s1.z); fr[7] = (short)f2bf(s1.w);
        A[mt][ks] = fr;
      }
    }

    const unsigned short* prow = xT + ((size_t)r * kB + gb0) * kE;
    const unsigned short* qrow = xT + ((size_t)c * kB + gb0) * kE;

#pragma unroll 2
    for (int bg = 0; bg < 16; ++bg) {
      const int bl = bg * 16 + col;  // local batch (0..255)
      const unsigned short* pb = prow + (size_t)bl * kE + quad * 8;
      const bf16x8 Bf0 = *(const bf16x8*)(pb);
      const bf16x8 Bf1 = *(const bf16x8*)(pb + 32);
      const unsigned short* qb = qrow + (size_t)bl * kE + quad * 4;
      const ushort4 q0 = *(const ushort4*)(qb);
      const ushort4 q1 = *(const ushort4*)(qb + 16);
      const ushort4 q2 = *(const ushort4*)(qb + 32);
      const ushort4 q3 = *(const ushort4*)(qb + 48);

      f32x4 acc[4];
#pragma unroll
      for (int mt = 0; mt < 4; ++mt) acc[mt] = (f32x4){0.f, 0.f, 0.f, 0.f};
#pragma unroll
      for (int mt = 0; mt < 4; ++mt) {
        acc[mt] = __builtin_amdgcn_mfma_f32_16x16x32_bf16(A[mt][0], Bf0, acc[mt], 0, 0, 0);
        acc[mt] = __builtin_amdgcn_mfma_f32_16x16x32_bf16(A[mt][1], Bf1, acc[mt], 0, 0, 0);
      }
      float dot = 0.f;
      dot = fmaf(acc[0][0], bf2f(q0.x), dot); dot = fmaf(acc[0][1], bf2f(q0.y), dot);
      dot = fmaf(acc[0][2], bf2f(q0.z), dot); dot = fmaf(acc[0][3], bf2f(q0.w), dot);
      dot = fmaf(acc[1][0], bf2f(q1.x), dot); dot = fmaf(acc[1][1], bf2f(q1.y), dot);
      dot = fmaf(acc[1][2], bf2f(q1.z), dot); dot = fmaf(acc[1][3], bf2f(q1.w), dot);
      dot = fmaf(acc[2][0], bf2f(q2.x), dot); dot = fmaf(acc[2][1], bf2f(q2.y), dot);
      dot = fmaf(acc[2][2], bf2f(q2.z), dot); dot = fmaf(acc[2][3], bf2f(q2.w), dot);
      dot = fmaf(acc[3][0], bf2f(q3.x), dot); dot = fmaf(acc[3][1], bf2f(q3.y), dot);
      dot = fmaf(acc[3][2], bf2f(q3.z), dot); dot = fmaf(acc[3][3], bf2f(q3.w), dot);
      dot += __shfl_xor(dot, 16, 64);
      dot += __shfl_xor(dot, 32, 64);
      if (quad == 0) dots[((rr * 256) + bl) * 4 + cc] = dot;  // 2-way banks: free
    }
  }
  __syncthreads();

  // out-phase: thread -> (b_local, rr); 4 masked scalar stores (4-consecutive-i run)
  const int ob  = t >> 1;
  const int orr = t & 1;
  const int orx = r0 + orr;
  const f32x4 dv = *(const f32x4*)&dots[((orr * 256) + ob) * 4];
  float* orow = out + (size_t)(gb0 + ob) * kP;
  const int ibase = orx * (79 - orx) / 2 - orx - 1;
#pragma unroll
  for (int occ = 0; occ < 4; ++occ) {
    const int ocp = c0 + occ;
    if (ocp > orx) orow[ibase + ocp] = dv[occ];  // written iff wave (orr,occ) was valid
  }
}

// ---- fallback (no ws): fp32 path ----
__global__ __launch_bounds__(256, 2)
void opn_fp32(const float* __restrict__ inp, const float* __restrict__ param,
              float* __restrict__ out) {
  const int i    = blockIdx.x;
  const int wave = threadIdx.x >> 6;
  const int lane = threadIdx.x & 63;
  const int b    = (blockIdx.y * 4 + wave) * 64 + lane;
  int rem = i, r = 0;
  while (rem >= kN - 1 - r) { rem -= kN - 1 - r; ++r; }
  const int c = r + 1 + rem;
  const float* pb = inp + (size_t)b * (kN * kE) + r * kE;
  const float* qb = inp + (size_t)b * (kN * kE) + c * kE;
  float p[kE];
#pragma unroll
  for (int e = 0; e < kE; ++e) p[e] = pb[e];
  float acc = 0.f;
  for (int f = 0; f < kE; ++f) {
    const float* Mrow = param + ((size_t)f * kP + i) * kE;
    float t0 = 0.f, t1 = 0.f, t2 = 0.f, t3 = 0.f;
#pragma unroll
    for (int e = 0; e < kE; e += 4) {
      t0 = fmaf(Mrow[e + 0], p[e + 0], t0);
      t1 = fmaf(Mrow[e + 1], p[e + 1], t1);
      t2 = fmaf(Mrow[e + 2], p[e + 2], t2);
      t3 = fmaf(Mrow[e + 3], p[e + 3], t3);
    }
    acc = fmaf((t0 + t1) + (t2 + t3), qb[f], acc);
  }
  out[(size_t)b * kP + i] = acc;
}
}  // namespace

extern "C" void kernel_launch(void* const* d_in, const int* in_sizes, int n_in,
                              void* d_out, int out_size, void* d_ws, size_t ws_size,
                              hipStream_t stream) {
  const float* inputs = (const float*)d_in[0];  // (B, N, E) fp32
  const float* param  = (const float*)d_in[1];  // (E, P, E) fp32
  float* out          = (float*)d_out;          // (B, 1, P) fp32

  const size_t xT_bytes = (size_t)kN * kB * kE * sizeof(unsigned short);  // 5.24 MB

  if (ws_size >= xT_bytes) {
    unsigned short* xT = (unsigned short*)d_ws;
    cvt_neb<<<(kN * kB * kE / 8) / 256, 256, 0, stream>>>(inputs, xT);
    // 110 tiles cover the upper triangle with 2x4 node tiles
    opn_tile<<<dim3(110, 4), 512, 0, stream>>>(xT, param, out);
  } else {
    opn_fp32<<<dim3(kP, 4), 256, 0, stream>>>(inputs, param, out);
  }
}

// Round 5
// 90.011 us; speedup vs baseline: 1.3743x; 1.3743x over previous
//
#include <hip/hip_runtime.h>

namespace {
constexpr int kB = 1024;
constexpr int kN = 40;
constexpr int kE = 64;
constexpr int kP = kN * (kN - 1) / 2;  // 780

using bf16x8 = __attribute__((ext_vector_type(8))) short;
using f32x4  = __attribute__((ext_vector_type(4))) float;

__device__ inline unsigned short f2bf(float x) {  // RNE fp32->bf16
  union { float f; unsigned u; } v; v.f = x;
  return (unsigned short)((v.u + 0x7FFFu + ((v.u >> 16) & 1u)) >> 16);
}
__device__ inline float bf2f(unsigned short u) {
  union { unsigned u; float f; } v; v.u = (unsigned)u << 16;
  return v.f;
}

// ---- x (B,N,E) fp32 -> MFMA B-frag layout xf: per (n, bg of 16 batches) a
// 1024-short block: [ks:2][lane:64][j:8], element = x[bg*16+(L&15)][n][ks*32+(L>>4)*8+j].
// Main kernel then loads fragments at base + lane*16B: fully dense.
__global__ __launch_bounds__(256) void cvt_frag(const float* __restrict__ in,
                                                unsigned short* __restrict__ xf) {
  const int n    = blockIdx.x;
  const int bgc  = blockIdx.y;      // 4 bgs per block
  const int t    = threadIdx.x;
  const int bgl  = t >> 6;
  const int L    = t & 63;
  const int col  = L & 15;
  const int quad = L >> 4;
  const int b    = (bgc * 4 + bgl) * 16 + col;
  const float* src    = in + ((size_t)b * kN + n) * kE + quad * 8;
  unsigned short* dst = xf + (((size_t)n * 64 + bgc * 4 + bgl) << 10) + L * 8;
  const float4 v0 = ((const float4*)src)[0];
  const float4 v1 = ((const float4*)src)[1];
  const float4 v2 = ((const float4*)(src + 32))[0];
  const float4 v3 = ((const float4*)(src + 32))[1];
  bf16x8 o0, o1;
  o0[0] = (short)f2bf(v0.x); o0[1] = (short)f2bf(v0.y);
  o0[2] = (short)f2bf(v0.z); o0[3] = (short)f2bf(v0.w);
  o0[4] = (short)f2bf(v1.x); o0[5] = (short)f2bf(v1.y);
  o0[6] = (short)f2bf(v1.z); o0[7] = (short)f2bf(v1.w);
  o1[0] = (short)f2bf(v2.x); o1[1] = (short)f2bf(v2.y);
  o1[2] = (short)f2bf(v2.z); o1[3] = (short)f2bf(v2.w);
  o1[4] = (short)f2bf(v3.x); o1[5] = (short)f2bf(v3.y);
  o1[6] = (short)f2bf(v3.z); o1[7] = (short)f2bf(v3.w);
  *(bf16x8*)dst         = o0;   // dense 1KB per wave
  *(bf16x8*)(dst + 512) = o1;
}

// ---- main: block = (r, c0..c0+1) x 256 batches; 4 waves = 2 cc x 2 batch-halves.
// All global loads dense; explicit reg double-buffer prefetch over 8 bgs/wave.
__global__ __launch_bounds__(256, 4)
void opn_pair(const unsigned short* __restrict__ xf,  // frag-layout bf16
              const float* __restrict__ param,         // (E,P,E) fp32
              float* __restrict__ out) {               // (B,1,P) fp32
  __shared__ short Ms[2 * 64 * 72];  // 2 pairs, stride 72 (pad)
  __shared__ float dots[256 * 2];    // [b_local][cc]

  const int t    = threadIdx.x;
  const int w    = t >> 6;
  const int L    = t & 63;
  const int col  = L & 15;
  const int quad = L >> 4;

  // decode blockIdx.x -> (r, c0): rows r=0..38, ceil((39-r)/2) c-pair tiles each (total 400)
  int tx = blockIdx.x, r = 0;
  for (;;) { const int nq = (40 - r) >> 1; if (tx < nq) break; tx -= nq; ++r; }
  const int c0  = r + 1 + tx * 2;
  const int ib  = r * (79 - r) / 2 + c0 - r - 1;  // pair index of (r, c0)
  const int gb0 = blockIdx.y * 256;

  // ---- stage M for up to 2 pairs into LDS (dense row reads, cvt bf16) ----
  {
    const int pp  = t >> 7;       // pair 0..1
    const int sub = t & 127;
    const int f   = sub >> 1;
    const int eh  = sub & 1;      // e-half (32 floats)
    if (c0 + pp <= kN - 1) {
      const float* src = param + ((size_t)f * kP + (ib + pp)) * kE + eh * 32;
      short* d = &Ms[pp * 4608 + f * 72 + eh * 32];
#pragma unroll
      for (int c8 = 0; c8 < 4; ++c8) {
        const float4 a0 = ((const float4*)src)[c8 * 2];
        const float4 a1 = ((const float4*)src)[c8 * 2 + 1];
        bf16x8 o;
        o[0] = (short)f2bf(a0.x); o[1] = (short)f2bf(a0.y);
        o[2] = (short)f2bf(a0.z); o[3] = (short)f2bf(a0.w);
        o[4] = (short)f2bf(a1.x); o[5] = (short)f2bf(a1.y);
        o[6] = (short)f2bf(a1.z); o[7] = (short)f2bf(a1.w);
        *(bf16x8*)(d + c8 * 8) = o;
      }
    }
  }
  __syncthreads();

  const int cc = w & 1;
  const int h  = w >> 1;
  const int c  = c0 + cc;

  if (c <= kN - 1) {
    // A-frags (R2-HW-verified mapping): A[m=16mt+col][k=quad*8+j+32ks]
    bf16x8 A[4][2];
#pragma unroll
    for (int mt = 0; mt < 4; ++mt)
#pragma unroll
      for (int ks = 0; ks < 2; ++ks)
        A[mt][ks] = *(const bf16x8*)&Ms[cc * 4608 + (16 * mt + col) * 72 + ks * 32 + quad * 8];

    const int bgg0 = blockIdx.y * 16 + h * 8;  // global bg base for this wave
    const unsigned short* pb = xf + (((size_t)r * 64 + bgg0) << 10);
    const unsigned short* qb = xf + (((size_t)c * 64 + bgg0) << 10);
    // q[b][16mt+quad*4+rho] sits dense in the frag layout at:
    const int qoff = (quad >> 1) * 128 + col * 8 + (quad & 1) * 4;

    bf16x8 B0[2], B1[2];
    ushort4 Q[2][4];
    B0[0]   = *(const bf16x8*)(pb + L * 8);
    B1[0]   = *(const bf16x8*)(pb + 512 + L * 8);
    Q[0][0] = *(const ushort4*)(qb + qoff);
    Q[0][1] = *(const ushort4*)(qb + 256 + qoff);
    Q[0][2] = *(const ushort4*)(qb + 512 + qoff);
    Q[0][3] = *(const ushort4*)(qb + 768 + qoff);

#pragma unroll
    for (int bg = 0; bg < 8; ++bg) {
      const int cb = bg & 1, nb = cb ^ 1;
      if (bg < 7) {  // prefetch next bg into alternate regs
        const unsigned short* pn = pb + ((size_t)(bg + 1) << 10);
        const unsigned short* qn = qb + ((size_t)(bg + 1) << 10);
        B0[nb]   = *(const bf16x8*)(pn + L * 8);
        B1[nb]   = *(const bf16x8*)(pn + 512 + L * 8);
        Q[nb][0] = *(const ushort4*)(qn + qoff);
        Q[nb][1] = *(const ushort4*)(qn + 256 + qoff);
        Q[nb][2] = *(const ushort4*)(qn + 512 + qoff);
        Q[nb][3] = *(const ushort4*)(qn + 768 + qoff);
      }
      f32x4 acc[4];
#pragma unroll
      for (int mt = 0; mt < 4; ++mt) acc[mt] = (f32x4){0.f, 0.f, 0.f, 0.f};
#pragma unroll
      for (int mt = 0; mt < 4; ++mt) {
        acc[mt] = __builtin_amdgcn_mfma_f32_16x16x32_bf16(A[mt][0], B0[cb], acc[mt], 0, 0, 0);
        acc[mt] = __builtin_amdgcn_mfma_f32_16x16x32_bf16(A[mt][1], B1[cb], acc[mt], 0, 0, 0);
      }
      float s[4];
#pragma unroll
      for (int mt = 0; mt < 4; ++mt) {
        const ushort4 qu = Q[cb][mt];
        float sm;
        sm = acc[mt][0] * bf2f(qu.x);
        sm = fmaf(acc[mt][1], bf2f(qu.y), sm);
        sm = fmaf(acc[mt][2], bf2f(qu.z), sm);
        sm = fmaf(acc[mt][3], bf2f(qu.w), sm);
        s[mt] = sm;
      }
      float dot = (s[0] + s[1]) + (s[2] + s[3]);
      dot += __shfl_xor(dot, 16, 64);
      dot += __shfl_xor(dot, 32, 64);
      if (quad == 0) dots[(h * 128 + bg * 16 + col) * 2 + cc] = dot;  // conflict-free
    }
  }
  __syncthreads();

  // out-phase: thread t -> batch t; 8B run per b (L2 write-merges adjacent blocks)
  const float2 dv = *(const float2*)&dots[t * 2];
  float* ob = out + (size_t)(gb0 + t) * kP + ib;
  ob[0] = dv.x;                        // c0 always valid (c0 >= r+1, c0 <= 39)
  if (c0 + 1 <= kN - 1) ob[1] = dv.y;
}

// ---- fallback (no ws): fp32 path ----
__global__ __launch_bounds__(256, 2)
void opn_fp32(const float* __restrict__ inp, const float* __restrict__ param,
              float* __restrict__ out) {
  const int i    = blockIdx.x;
  const int wave = threadIdx.x >> 6;
  const int lane = threadIdx.x & 63;
  const int b    = (blockIdx.y * 4 + wave) * 64 + lane;
  int rem = i, r = 0;
  while (rem >= kN - 1 - r) { rem -= kN - 1 - r; ++r; }
  const int c = r + 1 + rem;
  const float* pb = inp + (size_t)b * (kN * kE) + r * kE;
  const float* qb = inp + (size_t)b * (kN * kE) + c * kE;
  float p[kE];
#pragma unroll
  for (int e = 0; e < kE; ++e) p[e] = pb[e];
  float acc = 0.f;
  for (int f = 0; f < kE; ++f) {
    const float* Mrow = param + ((size_t)f * kP + i) * kE;
    float t0 = 0.f, t1 = 0.f, t2 = 0.f, t3 = 0.f;
#pragma unroll
    for (int e = 0; e < kE; e += 4) {
      t0 = fmaf(Mrow[e + 0], p[e + 0], t0);
      t1 = fmaf(Mrow[e + 1], p[e + 1], t1);
      t2 = fmaf(Mrow[e + 2], p[e + 2], t2);
      t3 = fmaf(Mrow[e + 3], p[e + 3], t3);
    }
    acc = fmaf((t0 + t1) + (t2 + t3), qb[f], acc);
  }
  out[(size_t)b * kP + i] = acc;
}
}  // namespace

extern "C" void kernel_launch(void* const* d_in, const int* in_sizes, int n_in,
                              void* d_out, int out_size, void* d_ws, size_t ws_size,
                              hipStream_t stream) {
  const float* inputs = (const float*)d_in[0];  // (B, N, E) fp32
  const float* param  = (const float*)d_in[1];  // (E, P, E) fp32
  float* out          = (float*)d_out;          // (B, 1, P) fp32

  const size_t xf_bytes = (size_t)kN * kB * kE * sizeof(unsigned short);  // 5.24 MB

  if (ws_size >= xf_bytes) {
    unsigned short* xf = (unsigned short*)d_ws;
    cvt_frag<<<dim3(kN, 16), 256, 0, stream>>>(inputs, xf);
    opn_pair<<<dim3(400, 4), 256, 0, stream>>>(xf, param, out);
  } else {
    opn_fp32<<<dim3(kP, 4), 256, 0, stream>>>(inputs, param, out);
  }
}

// Round 6
// 89.384 us; speedup vs baseline: 1.3839x; 1.0070x over previous
//
#include <hip/hip_runtime.h>

namespace {
constexpr int kB = 1024;
constexpr int kN = 40;
constexpr int kE = 64;
constexpr int kP = kN * (kN - 1) / 2;  // 780

using bf16x8 = __attribute__((ext_vector_type(8))) short;
using f32x4  = __attribute__((ext_vector_type(4))) float;

__device__ inline unsigned short f2bf(float x) {  // RNE fp32->bf16
  union { float f; unsigned u; } v; v.f = x;
  return (unsigned short)((v.u + 0x7FFFu + ((v.u >> 16) & 1u)) >> 16);
}
__device__ inline float bf2f(unsigned short u) {
  union { unsigned u; float f; } v; v.u = (unsigned)u << 16;
  return v.f;
}

// ---- fused prep ----
// blocks [0, 640): x (B,N,E) fp32 -> B-frag layout xf (R5-proven):
//   per (n,bg): 1024 shorts [ks:2][lane:64][j:8] = x[bg*16+(L&15)][n][ks*32+(L>>4)*8+j]
// blocks [640, 1420): param -> A-frag layout Af: per pair i: 4096 shorts,
//   chunk addr (mt*2+ks)*512 + L*8 holds M_i[16mt+(L&15)][ks*32+(L>>4)*8+j]
__global__ __launch_bounds__(256) void prep(const float* __restrict__ in,
                                            const float* __restrict__ param,
                                            unsigned short* __restrict__ xf,
                                            unsigned short* __restrict__ Af) {
  __shared__ short Ms[64 * 72];
  const int t = threadIdx.x;
  if (blockIdx.x < 640) {
    const int n    = blockIdx.x >> 4;
    const int bgc  = blockIdx.x & 15;
    const int bgl  = t >> 6;
    const int L    = t & 63;
    const int col  = L & 15;
    const int quad = L >> 4;
    const int b    = (bgc * 4 + bgl) * 16 + col;
    const float* src    = in + ((size_t)b * kN + n) * kE + quad * 8;
    unsigned short* dst = xf + (((size_t)n * 64 + bgc * 4 + bgl) << 10) + L * 8;
    const float4 v0 = ((const float4*)src)[0];
    const float4 v1 = ((const float4*)src)[1];
    const float4 v2 = ((const float4*)(src + 32))[0];
    const float4 v3 = ((const float4*)(src + 32))[1];
    bf16x8 o0, o1;
    o0[0] = (short)f2bf(v0.x); o0[1] = (short)f2bf(v0.y);
    o0[2] = (short)f2bf(v0.z); o0[3] = (short)f2bf(v0.w);
    o0[4] = (short)f2bf(v1.x); o0[5] = (short)f2bf(v1.y);
    o0[6] = (short)f2bf(v1.z); o0[7] = (short)f2bf(v1.w);
    o1[0] = (short)f2bf(v2.x); o1[1] = (short)f2bf(v2.y);
    o1[2] = (short)f2bf(v2.z); o1[3] = (short)f2bf(v2.w);
    o1[4] = (short)f2bf(v3.x); o1[5] = (short)f2bf(v3.y);
    o1[6] = (short)f2bf(v3.z); o1[7] = (short)f2bf(v3.w);
    *(bf16x8*)dst         = o0;
    *(bf16x8*)(dst + 512) = o1;
  } else {
    const int i = blockIdx.x - 640;  // pair index
    // phase A: 4-segment loads (16 lanes per f-row), cvt, stage in LDS
#pragma unroll
    for (int ph = 0; ph < 4; ++ph) {
      const int f  = ph * 16 + (t >> 4);
      const int e0 = (t & 15) * 4;
      const float4 v = *(const float4*)(param + ((size_t)f * kP + i) * kE + e0);
      short* d = &Ms[f * 72 + e0];
      d[0] = (short)f2bf(v.x); d[1] = (short)f2bf(v.y);
      d[2] = (short)f2bf(v.z); d[3] = (short)f2bf(v.w);
    }
    __syncthreads();
    // phase B: read A-frag pattern from LDS, store dense to Af
    unsigned short* base = Af + (size_t)i * 4096;
#pragma unroll
    for (int u = 0; u < 2; ++u) {
      const int chunk = t * 2 + u;       // 0..511
      const int L    = chunk & 63;
      const int mtks = chunk >> 6;       // mt*2+ks
      const int mt   = mtks >> 1, ks = mtks & 1;
      const int col  = L & 15, quad = L >> 4;
      const bf16x8 a = *(const bf16x8*)&Ms[(16 * mt + col) * 72 + ks * 32 + quad * 8];
      *(bf16x8*)(base + chunk * 8) = a;  // thread t: 32B dense
    }
  }
}

// ---- main: block = (r, c0..c0+1) x 256 batches; 4 waves = 2 cc x 2 batch-halves.
// All loads dense (A from Af, p/q from xf); reg double-buffer over 8 bgs/wave.
__global__ __launch_bounds__(256, 4)
void opn_pair2(const unsigned short* __restrict__ xf,
               const unsigned short* __restrict__ Af,
               float* __restrict__ out) {  // (B,1,P) fp32
  __shared__ float dots[256 * 2];  // [b_local][cc]

  const int t    = threadIdx.x;
  const int w    = t >> 6;
  const int L    = t & 63;
  const int col  = L & 15;
  const int quad = L >> 4;

  // decode blockIdx.x -> (r, c0): rows r=0..38, (40-r)>>1 c-pair tiles each (total 400)
  int tx = blockIdx.x, r = 0;
  for (;;) { const int nq = (40 - r) >> 1; if (tx < nq) break; tx -= nq; ++r; }
  const int c0  = r + 1 + tx * 2;
  const int ib  = r * (79 - r) / 2 + c0 - r - 1;  // pair index of (r, c0)
  const int gb0 = blockIdx.y * 256;

  const int cc = w & 1;
  const int h  = w >> 1;
  const int c  = c0 + cc;

  if (c <= kN - 1) {
    // A-frags: 8 dense 16B loads (R2-HW-verified mapping)
    const unsigned short* ab = Af + (size_t)(ib + cc) * 4096 + L * 8;
    bf16x8 A[4][2];
#pragma unroll
    for (int mt = 0; mt < 4; ++mt)
#pragma unroll
      for (int ks = 0; ks < 2; ++ks)
        A[mt][ks] = *(const bf16x8*)(ab + (mt * 2 + ks) * 512);

    const int bgg0 = blockIdx.y * 16 + h * 8;  // global bg base for this wave
    const unsigned short* pb = xf + (((size_t)r * 64 + bgg0) << 10);
    const unsigned short* qb = xf + (((size_t)c * 64 + bgg0) << 10);
    const int qoff = (quad >> 1) * 128 + col * 8 + (quad & 1) * 4;

    bf16x8 B0[2], B1[2];
    ushort4 Q[2][4];
    B0[0]   = *(const bf16x8*)(pb + L * 8);
    B1[0]   = *(const bf16x8*)(pb + 512 + L * 8);
    Q[0][0] = *(const ushort4*)(qb + qoff);
    Q[0][1] = *(const ushort4*)(qb + 256 + qoff);
    Q[0][2] = *(const ushort4*)(qb + 512 + qoff);
    Q[0][3] = *(const ushort4*)(qb + 768 + qoff);

#pragma unroll
    for (int bg = 0; bg < 8; ++bg) {
      const int cb = bg & 1, nb = cb ^ 1;
      if (bg < 7) {  // prefetch next bg into alternate regs
        const unsigned short* pn = pb + ((size_t)(bg + 1) << 10);
        const unsigned short* qn = qb + ((size_t)(bg + 1) << 10);
        B0[nb]   = *(const bf16x8*)(pn + L * 8);
        B1[nb]   = *(const bf16x8*)(pn + 512 + L * 8);
        Q[nb][0] = *(const ushort4*)(qn + qoff);
        Q[nb][1] = *(const ushort4*)(qn + 256 + qoff);
        Q[nb][2] = *(const ushort4*)(qn + 512 + qoff);
        Q[nb][3] = *(const ushort4*)(qn + 768 + qoff);
      }
      f32x4 acc[4];
#pragma unroll
      for (int mt = 0; mt < 4; ++mt) acc[mt] = (f32x4){0.f, 0.f, 0.f, 0.f};
#pragma unroll
      for (int mt = 0; mt < 4; ++mt) {
        acc[mt] = __builtin_amdgcn_mfma_f32_16x16x32_bf16(A[mt][0], B0[cb], acc[mt], 0, 0, 0);
        acc[mt] = __builtin_amdgcn_mfma_f32_16x16x32_bf16(A[mt][1], B1[cb], acc[mt], 0, 0, 0);
      }
      float s[4];
#pragma unroll
      for (int mt = 0; mt < 4; ++mt) {
        const ushort4 qu = Q[cb][mt];
        float sm;
        sm = acc[mt][0] * bf2f(qu.x);
        sm = fmaf(acc[mt][1], bf2f(qu.y), sm);
        sm = fmaf(acc[mt][2], bf2f(qu.z), sm);
        sm = fmaf(acc[mt][3], bf2f(qu.w), sm);
        s[mt] = sm;
      }
      float dot = (s[0] + s[1]) + (s[2] + s[3]);
      dot += __shfl_xor(dot, 16, 64);
      dot += __shfl_xor(dot, 32, 64);
      if (quad == 0) dots[(h * 128 + bg * 16 + col) * 2 + cc] = dot;
    }
  }
  __syncthreads();

  // out-phase: thread t -> batch t; 8B run per b (L2 write-merges adjacent blocks)
  const float2 dv = *(const float2*)&dots[t * 2];
  float* ob = out + (size_t)(gb0 + t) * kP + ib;
  ob[0] = dv.x;                        // c0 always valid
  if (c0 + 1 <= kN - 1) ob[1] = dv.y;
}

// ---- fallback (no ws): fp32 path ----
__global__ __launch_bounds__(256, 2)
void opn_fp32(const float* __restrict__ inp, const float* __restrict__ param,
              float* __restrict__ out) {
  const int i    = blockIdx.x;
  const int wave = threadIdx.x >> 6;
  const int lane = threadIdx.x & 63;
  const int b    = (blockIdx.y * 4 + wave) * 64 + lane;
  int rem = i, r = 0;
  while (rem >= kN - 1 - r) { rem -= kN - 1 - r; ++r; }
  const int c = r + 1 + rem;
  const float* pb = inp + (size_t)b * (kN * kE) + r * kE;
  const float* qb = inp + (size_t)b * (kN * kE) + c * kE;
  float p[kE];
#pragma unroll
  for (int e = 0; e < kE; ++e) p[e] = pb[e];
  float acc = 0.f;
  for (int f = 0; f < kE; ++f) {
    const float* Mrow = param + ((size_t)f * kP + i) * kE;
    float t0 = 0.f, t1 = 0.f, t2 = 0.f, t3 = 0.f;
#pragma unroll
    for (int e = 0; e < kE; e += 4) {
      t0 = fmaf(Mrow[e + 0], p[e + 0], t0);
      t1 = fmaf(Mrow[e + 1], p[e + 1], t1);
      t2 = fmaf(Mrow[e + 2], p[e + 2], t2);
      t3 = fmaf(Mrow[e + 3], p[e + 3], t3);
    }
    acc = fmaf((t0 + t1) + (t2 + t3), qb[f], acc);
  }
  out[(size_t)b * kP + i] = acc;
}
}  // namespace

extern "C" void kernel_launch(void* const* d_in, const int* in_sizes, int n_in,
                              void* d_out, int out_size, void* d_ws, size_t ws_size,
                              hipStream_t stream) {
  const float* inputs = (const float*)d_in[0];  // (B, N, E) fp32
  const float* param  = (const float*)d_in[1];  // (E, P, E) fp32
  float* out          = (float*)d_out;          // (B, 1, P) fp32

  const size_t xf_bytes = (size_t)kN * kB * kE * sizeof(unsigned short);   // 5.24 MB
  const size_t af_bytes = (size_t)kP * 4096 * sizeof(unsigned short);      // 6.39 MB

  if (ws_size >= xf_bytes + af_bytes) {
    unsigned short* xf = (unsigned short*)d_ws;
    unsigned short* Af = (unsigned short*)((char*)d_ws + xf_bytes);
    prep<<<640 + kP, 256, 0, stream>>>(inputs, param, xf, Af);
    opn_pair2<<<dim3(400, 4), 256, 0, stream>>>(xf, Af, out);
  } else {
    opn_fp32<<<dim3(kP, 4), 256, 0, stream>>>(inputs, param, out);
  }
}